// Round 10
// baseline (562.333 us; speedup 1.0000x reference)
//
#include <hip/hip_runtime.h>
#include <hip/hip_bf16.h>

namespace {

constexpr int Bb = 512;
constexpr int Tt = 512;
constexpr int OD = 32;
constexpr int AD = 8;
constexpr int WL = 10;
constexpr int Nn = Tt - WL + 1;   // 503
constexpr int CH = OD + AD;       // 40
constexpr int REC_T = 512;        // padded step count (64 chunks x 8)

constexpr float LOG2E = 1.4426950408889634f;

constexpr long SZ_PO = (long)Bb * Nn * 32;
constexpr long SZ_PR = (long)Bb * Nn * 2;
constexpr long OFF_POST   = 0;
constexpr long OFF_PRIORS = SZ_PO;
constexpr long OFF_POSTS  = OFF_PRIORS + SZ_PR;
constexpr long OFF_XTRAJ  = OFF_POSTS + SZ_PR;
constexpr long OFF_TGT    = OFF_XTRAJ + SZ_PR;
constexpr long OFF_LAB    = OFF_TGT + SZ_PO;

constexpr int PK_W1  = 0;
constexpr int PK_W2  = 26624;
constexpr int PK_W3  = 30720;
constexpr int PK_DW1 = 31744;
constexpr int PK_DW2 = 33792;
constexpr int PK_DW3 = 37888;
constexpr int PK_TOTAL = 39936;

typedef __attribute__((ext_vector_type(8))) short bf16x8;
typedef __attribute__((ext_vector_type(4))) float f32x4;

__device__ __align__(16) short g_pack[PK_TOTAL];

__device__ __forceinline__ f32x4 mfma16(bf16x8 a, bf16x8 b, f32x4 c) {
  return __builtin_amdgcn_mfma_f32_16x16x32_bf16(a, b, c, 0, 0, 0);
}

__device__ __forceinline__ unsigned short f2bf(float x) {
  unsigned int u = __float_as_uint(x);
  unsigned int r = u + 0x7fffu + ((u >> 16) & 1u);
  return (unsigned short)(r >> 16);
}

__device__ __forceinline__ float sigmoidf_(float x) {
  return 1.0f / (1.0f + __expf(-x));
}
__device__ __forceinline__ float tanh_(float x) {
  return 1.0f - 2.0f / (__expf(2.0f * x) + 1.0f);
}

template <int CTRL>
__device__ __forceinline__ float dpp_add(float x) {
  int y = __builtin_amdgcn_update_dpp(0, __float_as_int(x), CTRL, 0xf, 0xf, false);
  return x + __int_as_float(y);
}
template <int CTRL>
__device__ __forceinline__ float dpp_mov(float x) {
  return __int_as_float(
      __builtin_amdgcn_update_dpp(0, __float_as_int(x), CTRL, 0xf, 0xf, false));
}
__device__ __forceinline__ float row16_allsum(float x) {
  x = dpp_add<0xB1>(x);
  x = dpp_add<0x4E>(x);
  x = dpp_add<0x141>(x);
  x = dpp_add<0x140>(x);
  return x;
}

// ---------------- weight prepack ----------------
__global__ __launch_bounds__(256) void pack_kernel(
    const float* __restrict__ W1, const float* __restrict__ W2,
    const float* __restrict__ W3, const float* __restrict__ dW1,
    const float* __restrict__ dW2, const float* __restrict__ dW3) {
  const int idx = blockIdx.x * 256 + threadIdx.x;
  if (idx >= PK_TOTAL) return;
  float v = 0.0f;
  int base, r;
  if (idx < PK_W2) {
    base = PK_W1; r = idx - base;
    const int frag = r >> 9, inner = r & 511;
    const int lane = inner >> 3, j = inner & 7;
    const int kb = frag >> 2, jb = frag & 3;
    const int col = lane & 15;
    const int kp = kb * 32 + ((lane >> 4) << 3) + j;
    if (kp < 400) {
      const int w = kp / 40, c = kp - w * 40;
      v = W1[(c * 10 + w) * 64 + jb * 16 + col];
    }
  } else if (idx < PK_W3) {
    base = PK_W2; r = idx - base;
    const int frag = r >> 9, inner = r & 511;
    const int lane = inner >> 3, j = inner & 7;
    const int kb = frag >> 2, jb = frag & 3;
    const int col = lane & 15;
    const int k = kb * 32 + ((lane >> 4) << 3) + j;
    v = W2[k * 64 + jb * 16 + col];
  } else if (idx < PK_DW1) {
    base = PK_W3; r = idx - base;
    const int frag = r >> 9, inner = r & 511;
    const int lane = inner >> 3, j = inner & 7;
    const int kb = frag;
    const int col = lane & 15;
    const int k = kb * 32 + ((lane >> 4) << 3) + j;
    v = (col < 2) ? W3[k * 2 + col] : 0.0f;
  } else if (idx < PK_DW2) {
    base = PK_DW1; r = idx - base;
    const int frag = r >> 9, inner = r & 511;
    const int lane = inner >> 3, j = inner & 7;
    const int jb = frag;
    const int col = lane & 15;
    const int k = ((lane >> 4) << 3) + j;
    v = (k < 10) ? dW1[k * 64 + jb * 16 + col] : 0.0f;
  } else if (idx < PK_DW3) {
    base = PK_DW2; r = idx - base;
    const int frag = r >> 9, inner = r & 511;
    const int lane = inner >> 3, j = inner & 7;
    const int kb = frag >> 2, jb = frag & 3;
    const int col = lane & 15;
    const int k = kb * 32 + ((lane >> 4) << 3) + j;
    v = dW2[k * 64 + jb * 16 + col];
  } else {
    base = PK_DW3; r = idx - base;
    const int frag = r >> 9, inner = r & 511;
    const int lane = inner >> 3, j = inner & 7;
    const int kb = frag >> 1, jb = frag & 1;
    const int col = lane & 15;
    const int k = kb * 32 + ((lane >> 4) << 3) + j;
    v = dW3[k * 32 + jb * 16 + col];
  }
  g_pack[idx] = (short)f2bf(v);
}

// ---------------- standalone copy (fallback path only) ----------------
__global__ void copy_kernel(const float* __restrict__ obs,
                            const int* __restrict__ tlab,
                            float* __restrict__ out) {
  const int total4 = (int)(SZ_PO / 4);
  const int totalL = Bb * Nn;
  const int stride = gridDim.x * blockDim.x;
  float4* out4 = reinterpret_cast<float4*>(out + OFF_TGT);
  const float4* obs4 = reinterpret_cast<const float4*>(obs);
  for (int idx = blockIdx.x * blockDim.x + threadIdx.x;
       idx < total4 + totalL; idx += stride) {
    if (idx < total4) {
      const int b = idx / (Nn * 8);
      const int r = idx - b * (Nn * 8);
      const int n = r >> 3;
      const int c4 = r & 7;
      out4[idx] = obs4[((long)b * Tt + n + WL - 1) * 8 + c4];
    } else {
      const int j = idx - total4;
      const int b = j / Nn;
      const int n = j - b * Nn;
      out[OFF_LAB + j] = (float)tlab[(long)b * Tt + n + WL - 1];
    }
  }
}

// ---------------- encoder (MFMA) ----------------
__global__ __launch_bounds__(256) void enc_mfma(
    const float* __restrict__ obs, const float* __restrict__ act,
    const float* __restrict__ b1, const float* __restrict__ b2,
    const float* __restrict__ b3, float* __restrict__ out) {
  __shared__ __align__(16) unsigned short sA[74 * 40];
  __shared__ __align__(16) unsigned short sH1[64 * 64];
  __shared__ __align__(16) unsigned short sH2[64 * 64];
  const int b = blockIdx.x >> 3;
  const int n0 = (blockIdx.x & 7) << 6;
  const int tid = threadIdx.x;
  const int lane = tid & 63, wv = tid >> 6;
  const int q = lane >> 4, lr = lane & 15;
  const int nl = wv * 16 + lr;

  for (int e = tid; e < 74 * 40; e += 256) {
    const int row = e / 40, c = e - row * 40;
    int t = n0 + row; t = t < Tt ? t : Tt - 1;
    const float v = (c < OD) ? obs[((long)b * Tt + t) * OD + c]
                             : act[((long)b * Tt + t) * AD + c - OD];
    sA[e] = f2bf(v);
  }
  __syncthreads();

  const char* sAb = (const char*)sA;
  f32x4 acc[4] = {{0,0,0,0},{0,0,0,0},{0,0,0,0},{0,0,0,0}};
  {
    int c0 = q * 8, w = 0;
#pragma unroll
    for (int kb = 0; kb < 13; ++kb) {
      const bf16x8 a = *(const bf16x8*)(sAb + (nl + w) * 80 + c0 * 2);
#pragma unroll
      for (int jb = 0; jb < 4; ++jb) {
        const bf16x8 bw =
            *(const bf16x8*)&g_pack[PK_W1 + ((kb * 4 + jb) * 64 + lane) * 8];
        acc[jb] = mfma16(a, bw, acc[jb]);
      }
      c0 += 32;
      if (c0 >= 40) { c0 -= 40; ++w; }
    }
  }
  {
#pragma unroll
    for (int jb = 0; jb < 4; ++jb) {
      const float bb = b1[jb * 16 + lr];
#pragma unroll
      for (int r = 0; r < 4; ++r) {
        const int grow = wv * 16 + q * 4 + r;
        const int col = jb * 16 + lr;
        const float v = fmaxf(acc[jb][r] + bb, 0.0f);
        const int byte = (grow * 128 + col * 2) ^ ((grow & 7) << 4);
        *(unsigned short*)((char*)sH1 + byte) = f2bf(v);
      }
    }
  }
  __syncthreads();

  f32x4 ac2[4] = {{0,0,0,0},{0,0,0,0},{0,0,0,0},{0,0,0,0}};
#pragma unroll
  for (int kb = 0; kb < 2; ++kb) {
    const int byte = (nl * 128 + kb * 64 + q * 16) ^ ((lr & 7) << 4);
    const bf16x8 a = *(const bf16x8*)((const char*)sH1 + byte);
#pragma unroll
    for (int jb = 0; jb < 4; ++jb) {
      const bf16x8 bw =
          *(const bf16x8*)&g_pack[PK_W2 + ((kb * 4 + jb) * 64 + lane) * 8];
      ac2[jb] = mfma16(a, bw, ac2[jb]);
    }
  }
  {
#pragma unroll
    for (int jb = 0; jb < 4; ++jb) {
      const float bb = b2[jb * 16 + lr];
#pragma unroll
      for (int r = 0; r < 4; ++r) {
        const int grow = wv * 16 + q * 4 + r;
        const int col = jb * 16 + lr;
        const float v = fmaxf(ac2[jb][r] + bb, 0.0f);
        const int byte = (grow * 128 + col * 2) ^ ((grow & 7) << 4);
        *(unsigned short*)((char*)sH2 + byte) = f2bf(v);
      }
    }
  }
  __syncthreads();

  f32x4 ac3 = {0, 0, 0, 0};
#pragma unroll
  for (int kb = 0; kb < 2; ++kb) {
    const int byte = (nl * 128 + kb * 64 + q * 16) ^ ((lr & 7) << 4);
    const bf16x8 a = *(const bf16x8*)((const char*)sH2 + byte);
    const bf16x8 bw = *(const bf16x8*)&g_pack[PK_W3 + (kb * 64 + lane) * 8];
    ac3 = mfma16(a, bw, ac3);
  }
  if (lr < 2) {
    const float bb = b3[lr];
#pragma unroll
    for (int r = 0; r < 4; ++r) {
      const int grow = wv * 16 + q * 4 + r;
      const int n = n0 + grow;
      if (n < Nn) out[OFF_PRIORS + ((long)b * Nn + n) * 2 + lr] = ac3[r] + bb;
    }
  }
}

// ---------------- decoder (MFMA) ----------------
__global__ __launch_bounds__(256) void dec_mfma(
    const float* __restrict__ act, const float* __restrict__ b1,
    const float* __restrict__ b2, const float* __restrict__ b3,
    float* __restrict__ out) {
  __shared__ __align__(16) unsigned short sD[64 * 32];
  __shared__ __align__(16) unsigned short sH1[64 * 64];
  __shared__ __align__(16) unsigned short sH2[64 * 64];
  const int b = blockIdx.x >> 3;
  const int n0 = (blockIdx.x & 7) << 6;
  const int tid = threadIdx.x;
  const int lane = tid & 63, wv = tid >> 6;
  const int q = lane >> 4, lr = lane & 15;
  const int nl = wv * 16 + lr;
  const float* posts = out + OFF_POSTS;

  for (int e = tid; e < 64 * 32; e += 256) {
    const int row = e >> 5, c = e & 31;
    int n = n0 + row; n = n < Nn ? n : Nn - 1;
    float v = 0.0f;
    if (c < 2) v = posts[((long)b * Nn + n) * 2 + c];
    else if (c < 10) v = act[((long)b * Tt + n + WL - 1) * AD + c - 2];
    const int byte = (row * 64 + c * 2) ^ ((row & 3) << 4);
    *(unsigned short*)((char*)sD + byte) = f2bf(v);
  }
  __syncthreads();

  f32x4 acc[4] = {{0,0,0,0},{0,0,0,0},{0,0,0,0},{0,0,0,0}};
  {
    const int byte = (nl * 64 + q * 16) ^ ((nl & 3) << 4);
    const bf16x8 a = *(const bf16x8*)((const char*)sD + byte);
#pragma unroll
    for (int jb = 0; jb < 4; ++jb) {
      const bf16x8 bw = *(const bf16x8*)&g_pack[PK_DW1 + (jb * 64 + lane) * 8];
      acc[jb] = mfma16(a, bw, acc[jb]);
    }
  }
  {
#pragma unroll
    for (int jb = 0; jb < 4; ++jb) {
      const float bb = b1[jb * 16 + lr];
#pragma unroll
      for (int r = 0; r < 4; ++r) {
        const int grow = wv * 16 + q * 4 + r;
        const int col = jb * 16 + lr;
        const float v = fmaxf(acc[jb][r] + bb, 0.0f);
        const int byte = (grow * 128 + col * 2) ^ ((grow & 7) << 4);
        *(unsigned short*)((char*)sH1 + byte) = f2bf(v);
      }
    }
  }
  __syncthreads();

  f32x4 ac2[4] = {{0,0,0,0},{0,0,0,0},{0,0,0,0},{0,0,0,0}};
#pragma unroll
  for (int kb = 0; kb < 2; ++kb) {
    const int byte = (nl * 128 + kb * 64 + q * 16) ^ ((lr & 7) << 4);
    const bf16x8 a = *(const bf16x8*)((const char*)sH1 + byte);
#pragma unroll
    for (int jb = 0; jb < 4; ++jb) {
      const bf16x8 bw =
          *(const bf16x8*)&g_pack[PK_DW2 + ((kb * 4 + jb) * 64 + lane) * 8];
      ac2[jb] = mfma16(a, bw, ac2[jb]);
    }
  }
  {
#pragma unroll
    for (int jb = 0; jb < 4; ++jb) {
      const float bb = b2[jb * 16 + lr];
#pragma unroll
      for (int r = 0; r < 4; ++r) {
        const int grow = wv * 16 + q * 4 + r;
        const int col = jb * 16 + lr;
        const float v = fmaxf(ac2[jb][r] + bb, 0.0f);
        const int byte = (grow * 128 + col * 2) ^ ((grow & 7) << 4);
        *(unsigned short*)((char*)sH2 + byte) = f2bf(v);
      }
    }
  }
  __syncthreads();

  f32x4 ac3[2] = {{0,0,0,0},{0,0,0,0}};
#pragma unroll
  for (int kb = 0; kb < 2; ++kb) {
    const int byte = (nl * 128 + kb * 64 + q * 16) ^ ((lr & 7) << 4);
    const bf16x8 a = *(const bf16x8*)((const char*)sH2 + byte);
#pragma unroll
    for (int jb = 0; jb < 2; ++jb) {
      const bf16x8 bw =
          *(const bf16x8*)&g_pack[PK_DW3 + ((kb * 2 + jb) * 64 + lane) * 8];
      ac3[jb] = mfma16(a, bw, ac3[jb]);
    }
  }
#pragma unroll
  for (int jb = 0; jb < 2; ++jb) {
    const int o = jb * 16 + lr;
    const float bb = b3[o];
#pragma unroll
    for (int r = 0; r < 4; ++r) {
      const int grow = wv * 16 + q * 4 + r;
      const int n = n0 + grow;
      if (n < Nn) out[OFF_POST + ((long)b * Nn + n) * 32 + o] = ac3[jb][r] + bb;
    }
  }
}

// ---------------- gprep: 8-float records, prior folded into gate base ----------------
// rec[wgid(128)][t][sub(4)][8] = {gb0..gb5, mf0, pad}
//   mask=1: gb[q] = sc[q]*(acc + pr0*Wih[8][q] + pr1*Wih[9][q]), mf0 = 0
//   mask=0: gb[q] = sc[q]*acc,                                   mf0 = 1
__global__ __launch_bounds__(256) void gprep_kernel(
    const float* __restrict__ act, const int* __restrict__ mask,
    const float* __restrict__ Wih, const float* __restrict__ bih,
    const float* __restrict__ out, float* __restrict__ rec) {
  const int idx = blockIdx.x * 256 + threadIdx.x;
  const int total = Bb * REC_T;
  if (idx >= total) return;
  const int sub = idx & 3;
  const int t = (idx >> 2) & (REC_T - 1);
  const int wgid = idx >> 11;
  const int g = (wgid << 2) + sub;
  const float sc[6] = {-LOG2E, -LOG2E, -LOG2E, -LOG2E, 2.f * LOG2E, 2.f * LOG2E};
  float r[8];
#pragma unroll
  for (int i = 0; i < 8; ++i) r[i] = 0.0f;
  if (t < Nn - 1) {
    const float* a = act + ((long)g * Tt + WL - 1 + t) * AD;
    const float4 a0 = *reinterpret_cast<const float4*>(a);
    const float4 a1 = *reinterpret_cast<const float4*>(a + 4);
    const int m = mask[(long)g * Nn + t];
    const float2 pr =
        *reinterpret_cast<const float2*>(out + OFF_PRIORS + ((long)g * Nn + t) * 2);
#pragma unroll
    for (int q = 0; q < 6; ++q) {
      float acc = bih[q];
      acc = fmaf(a0.x, Wih[0 * 6 + q], acc);
      acc = fmaf(a0.y, Wih[1 * 6 + q], acc);
      acc = fmaf(a0.z, Wih[2 * 6 + q], acc);
      acc = fmaf(a0.w, Wih[3 * 6 + q], acc);
      acc = fmaf(a1.x, Wih[4 * 6 + q], acc);
      acc = fmaf(a1.y, Wih[5 * 6 + q], acc);
      acc = fmaf(a1.z, Wih[6 * 6 + q], acc);
      acc = fmaf(a1.w, Wih[7 * 6 + q], acc);
      if (m) {
        acc = fmaf(pr.x, Wih[8 * 6 + q], acc);
        acc = fmaf(pr.y, Wih[9 * 6 + q], acc);
      }
      r[q] = acc * sc[q];
    }
    r[6] = m ? 0.0f : 1.0f;
  }
  float4* o = reinterpret_cast<float4*>(rec + (long)idx * 8);
  o[0] = make_float4(r[0], r[1], r[2], r[3]);
  o[1] = make_float4(r[4], r[5], r[6], r[7]);
}

// ---------------- scan v8: 16 waves/block (4/SIMD) + LDS dbuf + exp2/rcp ----------------
// record: GA = {gb0..3}, GB = {gb4, gb5, mf0, pad}
#define SCAN_STEP(GA, GB, TG)                                               \
  do {                                                                      \
    const float sm0 = (GB).z * s0p;                                         \
    const float sm1 = (GB).z * s1p;                                         \
    float giq[6], ghq[6];                                                   \
    _Pragma("unroll") for (int q_ = 0; q_ < 6; ++q_) ghq[q_] =              \
        fmaf(x1p, whh1[q_], fmaf(x0p, whh0[q_], bhhv[q_]));                 \
    giq[0] = fmaf(sm1, wih9[0], fmaf(sm0, wih8[0], (GA).x));                \
    giq[1] = fmaf(sm1, wih9[1], fmaf(sm0, wih8[1], (GA).y));                \
    giq[2] = fmaf(sm1, wih9[2], fmaf(sm0, wih8[2], (GA).z));                \
    giq[3] = fmaf(sm1, wih9[3], fmaf(sm0, wih8[3], (GA).w));                \
    giq[4] = fmaf(sm1, wih9[4], fmaf(sm0, wih8[4], (GB).x));                \
    giq[5] = fmaf(sm1, wih9[5], fmaf(sm0, wih8[5], (GB).y));                \
    const float e0 = __builtin_amdgcn_exp2f(giq[0] + ghq[0]);               \
    const float e1 = __builtin_amdgcn_exp2f(giq[1] + ghq[1]);               \
    const float e2 = __builtin_amdgcn_exp2f(giq[2] + ghq[2]);               \
    const float e3 = __builtin_amdgcn_exp2f(giq[3] + ghq[3]);               \
    const float r0 = __builtin_amdgcn_rcpf(1.0f + e0);                      \
    const float r1 = __builtin_amdgcn_rcpf(1.0f + e1);                      \
    const float z0 = __builtin_amdgcn_rcpf(1.0f + e2);                      \
    const float z1 = __builtin_amdgcn_rcpf(1.0f + e3);                      \
    const float en0 = __builtin_amdgcn_exp2f(fmaf(r0, ghq[4], giq[4]));     \
    const float en1 = __builtin_amdgcn_exp2f(fmaf(r1, ghq[5], giq[5]));     \
    const float nn0 = fmaf(-2.0f, __builtin_amdgcn_rcpf(1.0f + en0), 1.0f); \
    const float nn1 = fmaf(-2.0f, __builtin_amdgcn_rcpf(1.0f + en1), 1.0f); \
    const float xn0 = fmaf(z0, x0p - nn0, nn0);                             \
    const float xn1 = fmaf(z1, x1p - nn1, nn1);                             \
    const float h1 = fmaxf(fmaf(xn1, w1c1, fmaf(xn0, w1c0, b1v)), 0.0f);    \
    const float t0 = h1;                                                    \
    const float t1 = dpp_mov<0xB1>(t0);                                     \
    const float t2 = dpp_mov<0x4E>(t0);                                     \
    const float t3 = dpp_mov<0x4E>(t1);                                     \
    const float t4 = dpp_mov<0x141>(t0);                                    \
    const float t5 = dpp_mov<0x141>(t1);                                    \
    const float t6 = dpp_mov<0x141>(t2);                                    \
    const float t7 = dpp_mov<0x141>(t3);                                    \
    const float t8 = dpp_mov<0x128>(t0);                                    \
    const float t9 = dpp_mov<0x128>(t1);                                    \
    const float t10 = dpp_mov<0x128>(t2);                                   \
    const float t11 = dpp_mov<0x128>(t3);                                   \
    const float t12 = dpp_mov<0x128>(t4);                                   \
    const float t13 = dpp_mov<0x128>(t5);                                   \
    const float t14 = dpp_mov<0x128>(t6);                                   \
    const float t15 = dpp_mov<0x128>(t7);                                   \
    float q0 = fmaf(t0, wg[0], b2v);                                        \
    q0 = fmaf(t1, wg[1], q0);                                               \
    q0 = fmaf(t2, wg[2], q0);                                               \
    q0 = fmaf(t3, wg[3], q0);                                               \
    float q1 = t4 * wg[4];                                                  \
    q1 = fmaf(t5, wg[5], q1);                                               \
    q1 = fmaf(t6, wg[6], q1);                                               \
    q1 = fmaf(t7, wg[7], q1);                                               \
    float q2 = t8 * wg[8];                                                  \
    q2 = fmaf(t9, wg[9], q2);                                               \
    q2 = fmaf(t10, wg[10], q2);                                             \
    q2 = fmaf(t11, wg[11], q2);                                             \
    float q3 = t12 * wg[12];                                                \
    q3 = fmaf(t13, wg[13], q3);                                             \
    q3 = fmaf(t14, wg[14], q3);                                             \
    q3 = fmaf(t15, wg[15], q3);                                             \
    const float h2 = fmaxf((q0 + q1) + (q2 + q3), 0.0f);                    \
    float p0 = row16_allsum(h2 * w3a);                                      \
    float p1 = row16_allsum(h2 * w3b);                                      \
    const float sn0 = p0 + b3a;                                             \
    const float sn1 = p1 + b3b;                                             \
    if (lane == 0 && (TG) < Nn - 1)                                         \
      *reinterpret_cast<float2*>(xw) = make_float2(xn0, xn1);               \
    if (lane == 1 && (TG) < Nn - 1)                                         \
      *reinterpret_cast<float2*>(sw) = make_float2(sn0, sn1);               \
    xw += 2;                                                                \
    sw += 2;                                                                \
    x0p = xn0;                                                              \
    x1p = xn1;                                                              \
    s0p = sn0;                                                              \
    s1p = sn1;                                                              \
  } while (0)

// per-wave staging: one float4/lane/chunk (chunk = 8 steps x 4 chains x 8 f)
#define LOADCH(C) stg = *reinterpret_cast<const float4*>(gsrc + (C) * 256 + wtid * 4)
#define WRITECH(BUF) *reinterpret_cast<float4*>(&slds[wv][BUF][wtid * 4]) = stg

__global__ __launch_bounds__(1024, 1) void scan6_kernel(
    const float* __restrict__ rec, const float* __restrict__ pW2,
    const float* __restrict__ pW1, const float* __restrict__ pb1,
    const float* __restrict__ pb2, const float* __restrict__ pW3,
    const float* __restrict__ pb3, const float* __restrict__ Wih,
    const float* __restrict__ Whh, const float* __restrict__ bhh,
    const float* __restrict__ obs, const int* __restrict__ tlab,
    float* __restrict__ out) {
  __shared__ __align__(16) float slds[16][2][256];
  const int tid = threadIdx.x;

  // blocks >= 8: fused copy (CUs the scan doesn't use)
  if (blockIdx.x >= 8) {
    const int total4 = (int)(SZ_PO / 4);
    const int totalL = Bb * Nn;
    const int stride = (gridDim.x - 8) * 1024;
    float4* out4 = reinterpret_cast<float4*>(out + OFF_TGT);
    const float4* obs4 = reinterpret_cast<const float4*>(obs);
    for (int idx = (blockIdx.x - 8) * 1024 + tid; idx < total4 + totalL;
         idx += stride) {
      if (idx < total4) {
        const int b = idx / (Nn * 8);
        const int r = idx - b * (Nn * 8);
        const int n = r >> 3;
        const int c4 = r & 7;
        out4[idx] = obs4[((long)b * Tt + n + WL - 1) * 8 + c4];
      } else {
        const int j = idx - total4;
        const int b = j / Nn;
        const int n = j - b * Nn;
        out[OFF_LAB + j] = (float)tlab[(long)b * Tt + n + WL - 1];
      }
    }
    return;
  }

  const int wv = tid >> 6;       // wave in block, 0..15
  const int wtid = tid & 63;     // lane in wave
  const int lane = wtid & 15;
  const int sub = wtid >> 4;     // chain in wave, 0..3
  const int wgid = blockIdx.x * 16 + wv;   // 0..127
  const int g = (wgid << 2) + sub;

  const float sc[6] = {-LOG2E, -LOG2E, -LOG2E, -LOG2E, 2.f * LOG2E, 2.f * LOG2E};
  float wih8[6], wih9[6], whh0[6], whh1[6], bhhv[6];
#pragma unroll
  for (int q = 0; q < 6; ++q) {
    wih8[q] = Wih[8 * 6 + q] * sc[q];
    wih9[q] = Wih[9 * 6 + q] * sc[q];
    whh0[q] = Whh[q] * sc[q];
    whh1[q] = Whh[6 + q] * sc[q];
    bhhv[q] = bhh[q] * sc[q];
  }
  const float w1c0 = pW1[lane], w1c1 = pW1[16 + lane], b1v = pb1[lane];
  constexpr int otab[16] = {0, 1, 2, 3, 7, 6, 5, 4, 8, 9, 10, 11, 15, 14, 13, 12};
  float wg[16];
#pragma unroll
  for (int i = 0; i < 16; ++i) wg[i] = pW2[(lane ^ otab[i]) * 16 + lane];
  const float b2v = pb2[lane];
  const float w3a = pW3[lane * 2], w3b = pW3[lane * 2 + 1];
  const float b3a = pb3[0], b3b = pb3[1];

  const float* priors = out + OFF_PRIORS;
  const long pbase = (long)g * Nn;
  const float* gsrc = rec + (long)wgid * (REC_T * 32);
  float* xw = out + OFF_XTRAJ + pbase * 2 + 2;
  float* sw = out + OFF_POSTS + pbase * 2 + 2;

  const float2 s0v = *reinterpret_cast<const float2*>(priors + pbase * 2);
  float x0p = 0.f, x1p = 0.f;
  float s0p = s0v.x, s1p = s0v.y;
  if (lane == 0)
    *reinterpret_cast<float2*>(out + OFF_XTRAJ + pbase * 2) =
        make_float2(0.f, 0.f);
  if (lane == 1)
    *reinterpret_cast<float2*>(out + OFF_POSTS + pbase * 2) =
        make_float2(s0p, s1p);

  float4 stg;
  LOADCH(0);
  WRITECH(0);
  LOADCH(1);   // chunk 1 in flight during chunk 0's compute

  // prefetch step (0,0)
  float4 cGA, cGB;
  {
    const float* rp = &slds[wv][0][(sub)*8];
    cGA = *reinterpret_cast<const float4*>(rp);
    cGB = *reinterpret_cast<const float4*>(rp + 4);
  }

  int tg = 0;
  for (int c = 0; c < 64; ++c) {
    const int buf = c & 1;
    if (c + 1 < 64) WRITECH((c + 1) & 1);
    if (c + 2 < 64) LOADCH(c + 2);
#pragma unroll
    for (int tl = 0; tl < 8; ++tl) {
      const float4 GA = cGA;
      const float4 GB = cGB;
      const int ntl = (tl + 1) & 7;
      const int nbuf = (tl == 7) ? (buf ^ 1) : buf;
      const float* rp = &slds[wv][nbuf][(ntl * 4 + sub) * 8];
      cGA = *reinterpret_cast<const float4*>(rp);
      cGB = *reinterpret_cast<const float4*>(rp + 4);
      SCAN_STEP(GA, GB, tg);
      ++tg;
    }
  }
}

// ---------------- fallback scan (no workspace) ----------------
__global__ __launch_bounds__(64) void scan_fb_kernel(
    const float* __restrict__ act, const int* __restrict__ mask,
    const float* __restrict__ Wih, const float* __restrict__ Whh,
    const float* __restrict__ bih, const float* __restrict__ bhh,
    const float* __restrict__ pW1, const float* __restrict__ pb1,
    const float* __restrict__ pW2, const float* __restrict__ pb2,
    const float* __restrict__ pW3, const float* __restrict__ pb3,
    float* __restrict__ out) {
  const int tid = threadIdx.x;
  const int lane = tid & 15;
  const int g = (blockIdx.x * 64 + tid) >> 4;

  float wih8[6], wih9[6], whh0[6], whh1[6], bhhv[6], bihv[6];
  float wihA[8][6];
#pragma unroll
  for (int q = 0; q < 6; ++q) {
    wih8[q] = Wih[8 * 6 + q];
    wih9[q] = Wih[9 * 6 + q];
    whh0[q] = Whh[q];
    whh1[q] = Whh[6 + q];
    bhhv[q] = bhh[q];
    bihv[q] = bih[q];
  }
#pragma unroll
  for (int i = 0; i < 8; ++i)
#pragma unroll
    for (int q = 0; q < 6; ++q) wihA[i][q] = Wih[i * 6 + q];

  const float w1c0 = pW1[lane], w1c1 = pW1[16 + lane], b1v = pb1[lane];
  float w2c[16];
#pragma unroll
  for (int k = 0; k < 16; ++k) w2c[k] = pW2[k * 16 + lane];
  const float b2v = pb2[lane];
  const float w3a = pW3[lane * 2], w3b = pW3[lane * 2 + 1];
  const float b3a = pb3[0], b3b = pb3[1];

  const float* priors = out + OFF_PRIORS;
  float* posts = out + OFF_POSTS;
  float* xtraj = out + OFF_XTRAJ;
  const long pbase = (long)g * Nn;
  const float* aptr = act + ((long)g * Tt + WL - 1) * 8;

  const float2 s0v = *reinterpret_cast<const float2*>(priors + pbase * 2);
  float x0p = 0.f, x1p = 0.f;
  float s0p = s0v.x, s1p = s0v.y;
  if (lane == 0)
    *reinterpret_cast<float2*>(xtraj + pbase * 2) = make_float2(0.f, 0.f);
  if (lane == 1)
    *reinterpret_cast<float2*>(posts + pbase * 2) = make_float2(s0p, s1p);

  float4 an0 = *reinterpret_cast<const float4*>(aptr);
  float4 an1 = *reinterpret_cast<const float4*>(aptr + 4);
  float2 prn = s0v;
  int mn = mask[pbase];

  for (int t = 0; t < Nn - 1; ++t) {
    const float4 a0 = an0, a1 = an1;
    const float2 pr = prn;
    const int m = mn;
    const int tn1 = (t + 1 < Nn - 1) ? t + 1 : Nn - 2;
    an0 = *reinterpret_cast<const float4*>(aptr + (long)tn1 * 8);
    an1 = *reinterpret_cast<const float4*>(aptr + (long)tn1 * 8 + 4);
    prn = *reinterpret_cast<const float2*>(priors + (pbase + t + 1) * 2);
    mn = mask[pbase + t + 1];

    const float st0 = m ? pr.x : s0p;
    const float st1 = m ? pr.y : s1p;

    float giq[6], ghq[6];
#pragma unroll
    for (int q = 0; q < 6; ++q) {
      float acc = bihv[q];
      acc = fmaf(a0.x, wihA[0][q], acc);
      acc = fmaf(a0.y, wihA[1][q], acc);
      acc = fmaf(a0.z, wihA[2][q], acc);
      acc = fmaf(a0.w, wihA[3][q], acc);
      acc = fmaf(a1.x, wihA[4][q], acc);
      acc = fmaf(a1.y, wihA[5][q], acc);
      acc = fmaf(a1.z, wihA[6][q], acc);
      acc = fmaf(a1.w, wihA[7][q], acc);
      giq[q] = fmaf(st1, wih9[q], fmaf(st0, wih8[q], acc));
      ghq[q] = fmaf(x1p, whh1[q], fmaf(x0p, whh0[q], bhhv[q]));
    }
    const float r0 = sigmoidf_(giq[0] + ghq[0]);
    const float r1 = sigmoidf_(giq[1] + ghq[1]);
    const float z0 = sigmoidf_(giq[2] + ghq[2]);
    const float z1 = sigmoidf_(giq[3] + ghq[3]);
    const float nn0 = tanh_(fmaf(r0, ghq[4], giq[4]));
    const float nn1 = tanh_(fmaf(r1, ghq[5], giq[5]));
    const float xn0 = fmaf(z0, x0p - nn0, nn0);
    const float xn1 = fmaf(z1, x1p - nn1, nn1);

    const float h1 = fmaxf(fmaf(xn1, w1c1, fmaf(xn0, w1c0, b1v)), 0.0f);
    float ha[16];
#pragma unroll
    for (int k = 0; k < 16; ++k) ha[k] = __shfl(h1, k, 16);
    float q0 = fmaf(ha[0], w2c[0], b2v);
    q0 = fmaf(ha[1], w2c[1], q0);
    q0 = fmaf(ha[2], w2c[2], q0);
    q0 = fmaf(ha[3], w2c[3], q0);
    float q1 = ha[4] * w2c[4];
    q1 = fmaf(ha[5], w2c[5], q1);
    q1 = fmaf(ha[6], w2c[6], q1);
    q1 = fmaf(ha[7], w2c[7], q1);
    float q2 = ha[8] * w2c[8];
    q2 = fmaf(ha[9], w2c[9], q2);
    q2 = fmaf(ha[10], w2c[10], q2);
    q2 = fmaf(ha[11], w2c[11], q2);
    float q3 = ha[12] * w2c[12];
    q3 = fmaf(ha[13], w2c[13], q3);
    q3 = fmaf(ha[14], w2c[14], q3);
    q3 = fmaf(ha[15], w2c[15], q3);
    const float h2 = fmaxf((q0 + q1) + (q2 + q3), 0.0f);

    float p0 = row16_allsum(h2 * w3a);
    float p1 = row16_allsum(h2 * w3b);
    const float sn0 = p0 + b3a;
    const float sn1 = p1 + b3b;

    if (lane == 0)
      *reinterpret_cast<float2*>(xtraj + (pbase + t + 1) * 2) =
          make_float2(xn0, xn1);
    if (lane == 1)
      *reinterpret_cast<float2*>(posts + (pbase + t + 1) * 2) =
          make_float2(sn0, sn1);
    x0p = xn0; x1p = xn1; s0p = sn0; s1p = sn1;
  }
}

}  // namespace

extern "C" void kernel_launch(void* const* d_in, const int* in_sizes, int n_in,
                              void* d_out, int out_size, void* d_ws, size_t ws_size,
                              hipStream_t stream) {
  const float* obs    = (const float*)d_in[0];
  const float* action = (const float*)d_in[1];
  const int* t_label  = (const int*)d_in[2];
  const int* mask     = (const int*)d_in[3];
  const float* enc_W1 = (const float*)d_in[4];
  const float* enc_b1 = (const float*)d_in[5];
  const float* enc_W2 = (const float*)d_in[6];
  const float* enc_b2 = (const float*)d_in[7];
  const float* enc_W3 = (const float*)d_in[8];
  const float* enc_b3 = (const float*)d_in[9];
  const float* gru_Wih = (const float*)d_in[10];
  const float* gru_Whh = (const float*)d_in[11];
  const float* gru_bih = (const float*)d_in[12];
  const float* gru_bhh = (const float*)d_in[13];
  const float* post_W1 = (const float*)d_in[14];
  const float* post_b1 = (const float*)d_in[15];
  const float* post_W2 = (const float*)d_in[16];
  const float* post_b2 = (const float*)d_in[17];
  const float* post_W3 = (const float*)d_in[18];
  const float* post_b3 = (const float*)d_in[19];
  const float* dec_W1 = (const float*)d_in[20];
  const float* dec_b1 = (const float*)d_in[21];
  const float* dec_W2 = (const float*)d_in[22];
  const float* dec_b2 = (const float*)d_in[23];
  const float* dec_W3 = (const float*)d_in[24];
  const float* dec_b3 = (const float*)d_in[25];
  float* out = (float*)d_out;

  pack_kernel<<<(PK_TOTAL + 255) / 256, 256, 0, stream>>>(
      enc_W1, enc_W2, enc_W3, dec_W1, dec_W2, dec_W3);

  enc_mfma<<<Bb * 8, 256, 0, stream>>>(obs, action, enc_b1, enc_b2, enc_b3,
                                       out);

  const size_t rec_bytes = (size_t)Bb * REC_T * 8 * sizeof(float);
  if (ws_size >= rec_bytes) {
    float* rec = (float*)d_ws;
    const int total = Bb * REC_T;
    gprep_kernel<<<(total + 255) / 256, 256, 0, stream>>>(
        action, mask, gru_Wih, gru_bih, out, rec);
    // scan blocks [0,8) (16 waves each) + fused copy blocks [8, 8+248)
    scan6_kernel<<<8 + 248, 1024, 0, stream>>>(
        rec, post_W2, post_W1, post_b1, post_b2, post_W3, post_b3, gru_Wih,
        gru_Whh, gru_bhh, obs, t_label, out);
  } else {
    scan_fb_kernel<<<128, 64, 0, stream>>>(
        action, mask, gru_Wih, gru_Whh, gru_bih, gru_bhh, post_W1, post_b1,
        post_W2, post_b2, post_W3, post_b3, out);
    copy_kernel<<<2048, 256, 0, stream>>>(obs, t_label, out);
  }

  dec_mfma<<<Bb * 8, 256, 0, stream>>>(action, dec_b1, dec_b2, dec_b3, out);
}

// Round 11
// 232.876 us; speedup vs baseline: 2.4147x; 2.4147x over previous
//
#include <hip/hip_runtime.h>
#include <hip/hip_bf16.h>

namespace {

constexpr int Bb = 512;
constexpr int Tt = 512;
constexpr int OD = 32;
constexpr int AD = 8;
constexpr int WL = 10;
constexpr int Nn = Tt - WL + 1;   // 503
constexpr int CH = OD + AD;       // 40
constexpr int REC_T = 512;        // padded step count (32 chunks x 16)

constexpr float LOG2E = 1.4426950408889634f;

constexpr long SZ_PO = (long)Bb * Nn * 32;
constexpr long SZ_PR = (long)Bb * Nn * 2;
constexpr long OFF_POST   = 0;
constexpr long OFF_PRIORS = SZ_PO;
constexpr long OFF_POSTS  = OFF_PRIORS + SZ_PR;
constexpr long OFF_XTRAJ  = OFF_POSTS + SZ_PR;
constexpr long OFF_TGT    = OFF_XTRAJ + SZ_PR;
constexpr long OFF_LAB    = OFF_TGT + SZ_PO;

constexpr int PK_W1  = 0;
constexpr int PK_W2  = 26624;
constexpr int PK_W3  = 30720;
constexpr int PK_DW1 = 31744;
constexpr int PK_DW2 = 33792;
constexpr int PK_DW3 = 37888;
constexpr int PK_TOTAL = 39936;

typedef __attribute__((ext_vector_type(8))) short bf16x8;
typedef __attribute__((ext_vector_type(4))) float f32x4;

__device__ __align__(16) short g_pack[PK_TOTAL];

__device__ __forceinline__ f32x4 mfma16(bf16x8 a, bf16x8 b, f32x4 c) {
  return __builtin_amdgcn_mfma_f32_16x16x32_bf16(a, b, c, 0, 0, 0);
}

__device__ __forceinline__ unsigned short f2bf(float x) {
  unsigned int u = __float_as_uint(x);
  unsigned int r = u + 0x7fffu + ((u >> 16) & 1u);
  return (unsigned short)(r >> 16);
}

__device__ __forceinline__ float sigmoidf_(float x) {
  return 1.0f / (1.0f + __expf(-x));
}
__device__ __forceinline__ float tanh_(float x) {
  return 1.0f - 2.0f / (__expf(2.0f * x) + 1.0f);
}

template <int CTRL>
__device__ __forceinline__ float dpp_add(float x) {
  int y = __builtin_amdgcn_update_dpp(0, __float_as_int(x), CTRL, 0xf, 0xf, false);
  return x + __int_as_float(y);
}
template <int CTRL>
__device__ __forceinline__ float dpp_mov(float x) {
  return __int_as_float(
      __builtin_amdgcn_update_dpp(0, __float_as_int(x), CTRL, 0xf, 0xf, false));
}
__device__ __forceinline__ float row16_allsum(float x) {
  x = dpp_add<0xB1>(x);
  x = dpp_add<0x4E>(x);
  x = dpp_add<0x141>(x);
  x = dpp_add<0x140>(x);
  return x;
}

// ---------------- weight prepack ----------------
__global__ __launch_bounds__(256) void pack_kernel(
    const float* __restrict__ W1, const float* __restrict__ W2,
    const float* __restrict__ W3, const float* __restrict__ dW1,
    const float* __restrict__ dW2, const float* __restrict__ dW3) {
  const int idx = blockIdx.x * 256 + threadIdx.x;
  if (idx >= PK_TOTAL) return;
  float v = 0.0f;
  int base, r;
  if (idx < PK_W2) {
    base = PK_W1; r = idx - base;
    const int frag = r >> 9, inner = r & 511;
    const int lane = inner >> 3, j = inner & 7;
    const int kb = frag >> 2, jb = frag & 3;
    const int col = lane & 15;
    const int kp = kb * 32 + ((lane >> 4) << 3) + j;
    if (kp < 400) {
      const int w = kp / 40, c = kp - w * 40;
      v = W1[(c * 10 + w) * 64 + jb * 16 + col];
    }
  } else if (idx < PK_W3) {
    base = PK_W2; r = idx - base;
    const int frag = r >> 9, inner = r & 511;
    const int lane = inner >> 3, j = inner & 7;
    const int kb = frag >> 2, jb = frag & 3;
    const int col = lane & 15;
    const int k = kb * 32 + ((lane >> 4) << 3) + j;
    v = W2[k * 64 + jb * 16 + col];
  } else if (idx < PK_DW1) {
    base = PK_W3; r = idx - base;
    const int frag = r >> 9, inner = r & 511;
    const int lane = inner >> 3, j = inner & 7;
    const int kb = frag;
    const int col = lane & 15;
    const int k = kb * 32 + ((lane >> 4) << 3) + j;
    v = (col < 2) ? W3[k * 2 + col] : 0.0f;
  } else if (idx < PK_DW2) {
    base = PK_DW1; r = idx - base;
    const int frag = r >> 9, inner = r & 511;
    const int lane = inner >> 3, j = inner & 7;
    const int jb = frag;
    const int col = lane & 15;
    const int k = ((lane >> 4) << 3) + j;
    v = (k < 10) ? dW1[k * 64 + jb * 16 + col] : 0.0f;
  } else if (idx < PK_DW3) {
    base = PK_DW2; r = idx - base;
    const int frag = r >> 9, inner = r & 511;
    const int lane = inner >> 3, j = inner & 7;
    const int kb = frag >> 2, jb = frag & 3;
    const int col = lane & 15;
    const int k = kb * 32 + ((lane >> 4) << 3) + j;
    v = dW2[k * 64 + jb * 16 + col];
  } else {
    base = PK_DW3; r = idx - base;
    const int frag = r >> 9, inner = r & 511;
    const int lane = inner >> 3, j = inner & 7;
    const int kb = frag >> 1, jb = frag & 1;
    const int col = lane & 15;
    const int k = kb * 32 + ((lane >> 4) << 3) + j;
    v = dW3[k * 32 + jb * 16 + col];
  }
  g_pack[idx] = (short)f2bf(v);
}

// ---------------- standalone copy (fallback path only) ----------------
__global__ void copy_kernel(const float* __restrict__ obs,
                            const int* __restrict__ tlab,
                            float* __restrict__ out) {
  const int total4 = (int)(SZ_PO / 4);
  const int totalL = Bb * Nn;
  const int stride = gridDim.x * blockDim.x;
  float4* out4 = reinterpret_cast<float4*>(out + OFF_TGT);
  const float4* obs4 = reinterpret_cast<const float4*>(obs);
  for (int idx = blockIdx.x * blockDim.x + threadIdx.x;
       idx < total4 + totalL; idx += stride) {
    if (idx < total4) {
      const int b = idx / (Nn * 8);
      const int r = idx - b * (Nn * 8);
      const int n = r >> 3;
      const int c4 = r & 7;
      out4[idx] = obs4[((long)b * Tt + n + WL - 1) * 8 + c4];
    } else {
      const int j = idx - total4;
      const int b = j / Nn;
      const int n = j - b * Nn;
      out[OFF_LAB + j] = (float)tlab[(long)b * Tt + n + WL - 1];
    }
  }
}

// ---------------- encoder (MFMA) + fused scan-record generation ----------------
// After computing priors, each block also emits the 8-float folded scan records
// for its 64 t's:
//   mask=1: gb[q] = sc[q]*(gia + pr0*Wih[8][q] + pr1*Wih[9][q]), mf0 = 0
//   mask=0: gb[q] = sc[q]*gia,                                   mf0 = 1
// rec layout: idx = (b>>2)*2048 + t*4 + (b&3), 8 floats each.
__global__ __launch_bounds__(256) void enc_mfma(
    const float* __restrict__ obs, const float* __restrict__ act,
    const float* __restrict__ b1, const float* __restrict__ b2,
    const float* __restrict__ b3, const int* __restrict__ mask,
    const float* __restrict__ Wih, const float* __restrict__ bih,
    float* __restrict__ rec, float* __restrict__ out) {
  __shared__ __align__(16) unsigned short sA[74 * 40];
  __shared__ __align__(16) unsigned short sH1[64 * 64];
  __shared__ __align__(16) unsigned short sH2[64 * 64];
  __shared__ float sPr[64][2];
  const int b = blockIdx.x >> 3;
  const int n0 = (blockIdx.x & 7) << 6;
  const int tid = threadIdx.x;
  const int lane = tid & 63, wv = tid >> 6;
  const int q = lane >> 4, lr = lane & 15;
  const int nl = wv * 16 + lr;

  for (int e = tid; e < 74 * 40; e += 256) {
    const int row = e / 40, c = e - row * 40;
    int t = n0 + row; t = t < Tt ? t : Tt - 1;
    const float v = (c < OD) ? obs[((long)b * Tt + t) * OD + c]
                             : act[((long)b * Tt + t) * AD + c - OD];
    sA[e] = f2bf(v);
  }
  __syncthreads();

  const char* sAb = (const char*)sA;
  f32x4 acc[4] = {{0,0,0,0},{0,0,0,0},{0,0,0,0},{0,0,0,0}};
  {
    int c0 = q * 8, w = 0;
#pragma unroll
    for (int kb = 0; kb < 13; ++kb) {
      const bf16x8 a = *(const bf16x8*)(sAb + (nl + w) * 80 + c0 * 2);
#pragma unroll
      for (int jb = 0; jb < 4; ++jb) {
        const bf16x8 bw =
            *(const bf16x8*)&g_pack[PK_W1 + ((kb * 4 + jb) * 64 + lane) * 8];
        acc[jb] = mfma16(a, bw, acc[jb]);
      }
      c0 += 32;
      if (c0 >= 40) { c0 -= 40; ++w; }
    }
  }
  {
#pragma unroll
    for (int jb = 0; jb < 4; ++jb) {
      const float bb = b1[jb * 16 + lr];
#pragma unroll
      for (int r = 0; r < 4; ++r) {
        const int grow = wv * 16 + q * 4 + r;
        const int col = jb * 16 + lr;
        const float v = fmaxf(acc[jb][r] + bb, 0.0f);
        const int byte = (grow * 128 + col * 2) ^ ((grow & 7) << 4);
        *(unsigned short*)((char*)sH1 + byte) = f2bf(v);
      }
    }
  }
  __syncthreads();

  f32x4 ac2[4] = {{0,0,0,0},{0,0,0,0},{0,0,0,0},{0,0,0,0}};
#pragma unroll
  for (int kb = 0; kb < 2; ++kb) {
    const int byte = (nl * 128 + kb * 64 + q * 16) ^ ((lr & 7) << 4);
    const bf16x8 a = *(const bf16x8*)((const char*)sH1 + byte);
#pragma unroll
    for (int jb = 0; jb < 4; ++jb) {
      const bf16x8 bw =
          *(const bf16x8*)&g_pack[PK_W2 + ((kb * 4 + jb) * 64 + lane) * 8];
      ac2[jb] = mfma16(a, bw, ac2[jb]);
    }
  }
  {
#pragma unroll
    for (int jb = 0; jb < 4; ++jb) {
      const float bb = b2[jb * 16 + lr];
#pragma unroll
      for (int r = 0; r < 4; ++r) {
        const int grow = wv * 16 + q * 4 + r;
        const int col = jb * 16 + lr;
        const float v = fmaxf(ac2[jb][r] + bb, 0.0f);
        const int byte = (grow * 128 + col * 2) ^ ((grow & 7) << 4);
        *(unsigned short*)((char*)sH2 + byte) = f2bf(v);
      }
    }
  }
  __syncthreads();

  f32x4 ac3 = {0, 0, 0, 0};
#pragma unroll
  for (int kb = 0; kb < 2; ++kb) {
    const int byte = (nl * 128 + kb * 64 + q * 16) ^ ((lr & 7) << 4);
    const bf16x8 a = *(const bf16x8*)((const char*)sH2 + byte);
    const bf16x8 bw = *(const bf16x8*)&g_pack[PK_W3 + (kb * 64 + lane) * 8];
    ac3 = mfma16(a, bw, ac3);
  }
  if (lr < 2) {
    const float bb = b3[lr];
#pragma unroll
    for (int r = 0; r < 4; ++r) {
      const int grow = wv * 16 + q * 4 + r;
      const int n = n0 + grow;
      const float v = ac3[r] + bb;
      sPr[grow][lr] = v;
      if (n < Nn) out[OFF_PRIORS + ((long)b * Nn + n) * 2 + lr] = v;
    }
  }

  if (rec != nullptr) {
    __syncthreads();
    if (tid < 64) {
      const int t = n0 + tid;
      const float sc[6] = {-LOG2E, -LOG2E, -LOG2E, -LOG2E,
                           2.f * LOG2E, 2.f * LOG2E};
      float r[8];
#pragma unroll
      for (int i = 0; i < 8; ++i) r[i] = 0.0f;
      if (t < Nn - 1) {
        const float* a = act + ((long)b * Tt + WL - 1 + t) * AD;
        const float4 a0 = *reinterpret_cast<const float4*>(a);
        const float4 a1 = *reinterpret_cast<const float4*>(a + 4);
        const int m = mask[(long)b * Nn + t];
        const float pr0 = sPr[tid][0];
        const float pr1 = sPr[tid][1];
#pragma unroll
        for (int qq = 0; qq < 6; ++qq) {
          float acv = bih[qq];
          acv = fmaf(a0.x, Wih[0 * 6 + qq], acv);
          acv = fmaf(a0.y, Wih[1 * 6 + qq], acv);
          acv = fmaf(a0.z, Wih[2 * 6 + qq], acv);
          acv = fmaf(a0.w, Wih[3 * 6 + qq], acv);
          acv = fmaf(a1.x, Wih[4 * 6 + qq], acv);
          acv = fmaf(a1.y, Wih[5 * 6 + qq], acv);
          acv = fmaf(a1.z, Wih[6 * 6 + qq], acv);
          acv = fmaf(a1.w, Wih[7 * 6 + qq], acv);
          if (m) {
            acv = fmaf(pr0, Wih[8 * 6 + qq], acv);
            acv = fmaf(pr1, Wih[9 * 6 + qq], acv);
          }
          r[qq] = acv * sc[qq];
        }
        r[6] = m ? 0.0f : 1.0f;
      }
      const long ridx = ((long)(b >> 2) * 2048 + t * 4 + (b & 3)) * 8;
      float4* o = reinterpret_cast<float4*>(rec + ridx);
      o[0] = make_float4(r[0], r[1], r[2], r[3]);
      o[1] = make_float4(r[4], r[5], r[6], r[7]);
    }
  }
}

// ---------------- decoder (MFMA) ----------------
__global__ __launch_bounds__(256) void dec_mfma(
    const float* __restrict__ act, const float* __restrict__ b1,
    const float* __restrict__ b2, const float* __restrict__ b3,
    float* __restrict__ out) {
  __shared__ __align__(16) unsigned short sD[64 * 32];
  __shared__ __align__(16) unsigned short sH1[64 * 64];
  __shared__ __align__(16) unsigned short sH2[64 * 64];
  const int b = blockIdx.x >> 3;
  const int n0 = (blockIdx.x & 7) << 6;
  const int tid = threadIdx.x;
  const int lane = tid & 63, wv = tid >> 6;
  const int q = lane >> 4, lr = lane & 15;
  const int nl = wv * 16 + lr;
  const float* posts = out + OFF_POSTS;

  for (int e = tid; e < 64 * 32; e += 256) {
    const int row = e >> 5, c = e & 31;
    int n = n0 + row; n = n < Nn ? n : Nn - 1;
    float v = 0.0f;
    if (c < 2) v = posts[((long)b * Nn + n) * 2 + c];
    else if (c < 10) v = act[((long)b * Tt + n + WL - 1) * AD + c - 2];
    const int byte = (row * 64 + c * 2) ^ ((row & 3) << 4);
    *(unsigned short*)((char*)sD + byte) = f2bf(v);
  }
  __syncthreads();

  f32x4 acc[4] = {{0,0,0,0},{0,0,0,0},{0,0,0,0},{0,0,0,0}};
  {
    const int byte = (nl * 64 + q * 16) ^ ((nl & 3) << 4);
    const bf16x8 a = *(const bf16x8*)((const char*)sD + byte);
#pragma unroll
    for (int jb = 0; jb < 4; ++jb) {
      const bf16x8 bw = *(const bf16x8*)&g_pack[PK_DW1 + (jb * 64 + lane) * 8];
      acc[jb] = mfma16(a, bw, acc[jb]);
    }
  }
  {
#pragma unroll
    for (int jb = 0; jb < 4; ++jb) {
      const float bb = b1[jb * 16 + lr];
#pragma unroll
      for (int r = 0; r < 4; ++r) {
        const int grow = wv * 16 + q * 4 + r;
        const int col = jb * 16 + lr;
        const float v = fmaxf(acc[jb][r] + bb, 0.0f);
        const int byte = (grow * 128 + col * 2) ^ ((grow & 7) << 4);
        *(unsigned short*)((char*)sH1 + byte) = f2bf(v);
      }
    }
  }
  __syncthreads();

  f32x4 ac2[4] = {{0,0,0,0},{0,0,0,0},{0,0,0,0},{0,0,0,0}};
#pragma unroll
  for (int kb = 0; kb < 2; ++kb) {
    const int byte = (nl * 128 + kb * 64 + q * 16) ^ ((lr & 7) << 4);
    const bf16x8 a = *(const bf16x8*)((const char*)sH1 + byte);
#pragma unroll
    for (int jb = 0; jb < 4; ++jb) {
      const bf16x8 bw =
          *(const bf16x8*)&g_pack[PK_DW2 + ((kb * 4 + jb) * 64 + lane) * 8];
      ac2[jb] = mfma16(a, bw, ac2[jb]);
    }
  }
  {
#pragma unroll
    for (int jb = 0; jb < 4; ++jb) {
      const float bb = b2[jb * 16 + lr];
#pragma unroll
      for (int r = 0; r < 4; ++r) {
        const int grow = wv * 16 + q * 4 + r;
        const int col = jb * 16 + lr;
        const float v = fmaxf(ac2[jb][r] + bb, 0.0f);
        const int byte = (grow * 128 + col * 2) ^ ((grow & 7) << 4);
        *(unsigned short*)((char*)sH2 + byte) = f2bf(v);
      }
    }
  }
  __syncthreads();

  f32x4 ac3[2] = {{0,0,0,0},{0,0,0,0}};
#pragma unroll
  for (int kb = 0; kb < 2; ++kb) {
    const int byte = (nl * 128 + kb * 64 + q * 16) ^ ((lr & 7) << 4);
    const bf16x8 a = *(const bf16x8*)((const char*)sH2 + byte);
#pragma unroll
    for (int jb = 0; jb < 2; ++jb) {
      const bf16x8 bw =
          *(const bf16x8*)&g_pack[PK_DW3 + ((kb * 2 + jb) * 64 + lane) * 8];
      ac3[jb] = mfma16(a, bw, ac3[jb]);
    }
  }
#pragma unroll
  for (int jb = 0; jb < 2; ++jb) {
    const int o = jb * 16 + lr;
    const float bb = b3[o];
#pragma unroll
    for (int r = 0; r < 4; ++r) {
      const int grow = wv * 16 + q * 4 + r;
      const int n = n0 + grow;
      if (n < Nn) out[OFF_POST + ((long)b * Nn + n) * 32 + o] = ac3[jb][r] + bb;
    }
  }
}

// ---------------- scan: 1 wave/CU, 8-float folded records, fused copy ----------------
// record: GA = {gb0..3}, GB = {gb4, gb5, mf0, pad}
#define SCAN_STEP(GA, GB, TG)                                               \
  do {                                                                      \
    const float sm0 = (GB).z * s0p;                                         \
    const float sm1 = (GB).z * s1p;                                         \
    float giq[6], ghq[6];                                                   \
    _Pragma("unroll") for (int q_ = 0; q_ < 6; ++q_) ghq[q_] =              \
        fmaf(x1p, whh1[q_], fmaf(x0p, whh0[q_], bhhv[q_]));                 \
    giq[0] = fmaf(sm1, wih9[0], fmaf(sm0, wih8[0], (GA).x));                \
    giq[1] = fmaf(sm1, wih9[1], fmaf(sm0, wih8[1], (GA).y));                \
    giq[2] = fmaf(sm1, wih9[2], fmaf(sm0, wih8[2], (GA).z));                \
    giq[3] = fmaf(sm1, wih9[3], fmaf(sm0, wih8[3], (GA).w));                \
    giq[4] = fmaf(sm1, wih9[4], fmaf(sm0, wih8[4], (GB).x));                \
    giq[5] = fmaf(sm1, wih9[5], fmaf(sm0, wih8[5], (GB).y));                \
    const float e0 = __builtin_amdgcn_exp2f(giq[0] + ghq[0]);               \
    const float e1 = __builtin_amdgcn_exp2f(giq[1] + ghq[1]);               \
    const float e2 = __builtin_amdgcn_exp2f(giq[2] + ghq[2]);               \
    const float e3 = __builtin_amdgcn_exp2f(giq[3] + ghq[3]);               \
    const float r0 = __builtin_amdgcn_rcpf(1.0f + e0);                      \
    const float r1 = __builtin_amdgcn_rcpf(1.0f + e1);                      \
    const float z0 = __builtin_amdgcn_rcpf(1.0f + e2);                      \
    const float z1 = __builtin_amdgcn_rcpf(1.0f + e3);                      \
    const float en0 = __builtin_amdgcn_exp2f(fmaf(r0, ghq[4], giq[4]));     \
    const float en1 = __builtin_amdgcn_exp2f(fmaf(r1, ghq[5], giq[5]));     \
    const float nn0 = fmaf(-2.0f, __builtin_amdgcn_rcpf(1.0f + en0), 1.0f); \
    const float nn1 = fmaf(-2.0f, __builtin_amdgcn_rcpf(1.0f + en1), 1.0f); \
    const float xn0 = fmaf(z0, x0p - nn0, nn0);                             \
    const float xn1 = fmaf(z1, x1p - nn1, nn1);                             \
    const float h1 = fmaxf(fmaf(xn1, w1c1, fmaf(xn0, w1c0, b1v)), 0.0f);    \
    const float t0 = h1;                                                    \
    const float t1 = dpp_mov<0xB1>(t0);                                     \
    const float t2 = dpp_mov<0x4E>(t0);                                     \
    const float t3 = dpp_mov<0x4E>(t1);                                     \
    const float t4 = dpp_mov<0x141>(t0);                                    \
    const float t5 = dpp_mov<0x141>(t1);                                    \
    const float t6 = dpp_mov<0x141>(t2);                                    \
    const float t7 = dpp_mov<0x141>(t3);                                    \
    const float t8 = dpp_mov<0x128>(t0);                                    \
    const float t9 = dpp_mov<0x128>(t1);                                    \
    const float t10 = dpp_mov<0x128>(t2);                                   \
    const float t11 = dpp_mov<0x128>(t3);                                   \
    const float t12 = dpp_mov<0x128>(t4);                                   \
    const float t13 = dpp_mov<0x128>(t5);                                   \
    const float t14 = dpp_mov<0x128>(t6);                                   \
    const float t15 = dpp_mov<0x128>(t7);                                   \
    float q0 = fmaf(t0, wg[0], b2v);                                        \
    q0 = fmaf(t1, wg[1], q0);                                               \
    q0 = fmaf(t2, wg[2], q0);                                               \
    q0 = fmaf(t3, wg[3], q0);                                               \
    float q1 = t4 * wg[4];                                                  \
    q1 = fmaf(t5, wg[5], q1);                                               \
    q1 = fmaf(t6, wg[6], q1);                                               \
    q1 = fmaf(t7, wg[7], q1);                                               \
    float q2 = t8 * wg[8];                                                  \
    q2 = fmaf(t9, wg[9], q2);                                               \
    q2 = fmaf(t10, wg[10], q2);                                             \
    q2 = fmaf(t11, wg[11], q2);                                             \
    float q3 = t12 * wg[12];                                                \
    q3 = fmaf(t13, wg[13], q3);                                             \
    q3 = fmaf(t14, wg[14], q3);                                             \
    q3 = fmaf(t15, wg[15], q3);                                             \
    const float h2 = fmaxf((q0 + q1) + (q2 + q3), 0.0f);                    \
    float p0 = row16_allsum(h2 * w3a);                                      \
    float p1 = row16_allsum(h2 * w3b);                                      \
    const float sn0 = p0 + b3a;                                             \
    const float sn1 = p1 + b3b;                                             \
    if (lane == 0 && (TG) < Nn - 1)                                         \
      *reinterpret_cast<float2*>(xw) = make_float2(xn0, xn1);               \
    if (lane == 1 && (TG) < Nn - 1)                                         \
      *reinterpret_cast<float2*>(sw) = make_float2(sn0, sn1);               \
    xw += 2;                                                                \
    sw += 2;                                                                \
    x0p = xn0;                                                              \
    x1p = xn1;                                                              \
    s0p = sn0;                                                              \
    s1p = sn1;                                                              \
  } while (0)

// chunk = 16 steps x 4 chains x 8 floats = 512 floats; 8 floats/lane
#define LOADCH(C)                                                      \
  do {                                                                 \
    const float* p_ = gsrc + (C) * 512 + tid * 8;                      \
    st0 = *reinterpret_cast<const float4*>(p_);                        \
    st1 = *reinterpret_cast<const float4*>(p_ + 4);                    \
  } while (0)
#define WRITECH(BUF)                                                   \
  do {                                                                 \
    float* q_ = &slds[BUF][tid * 8];                                   \
    *reinterpret_cast<float4*>(q_) = st0;                              \
    *reinterpret_cast<float4*>(q_ + 4) = st1;                          \
  } while (0)

__global__ __launch_bounds__(64, 1) void scan4_kernel(
    const float* __restrict__ rec, const float* __restrict__ pW2,
    const float* __restrict__ pW1, const float* __restrict__ pb1,
    const float* __restrict__ pb2, const float* __restrict__ pW3,
    const float* __restrict__ pb3, const float* __restrict__ Wih,
    const float* __restrict__ Whh, const float* __restrict__ bhh,
    const float* __restrict__ obs, const int* __restrict__ tlab,
    float* __restrict__ out) {
  __shared__ __align__(16) float slds[2][512];
  const int tid = threadIdx.x;

  // blocks >= 128: fused copy (runs on CUs the scan leaves idle)
  if (blockIdx.x >= 128) {
    const int total4 = (int)(SZ_PO / 4);
    const int totalL = Bb * Nn;
    const int stride = (gridDim.x - 128) * 64;
    float4* out4 = reinterpret_cast<float4*>(out + OFF_TGT);
    const float4* obs4 = reinterpret_cast<const float4*>(obs);
    for (int idx = (blockIdx.x - 128) * 64 + tid; idx < total4 + totalL;
         idx += stride) {
      if (idx < total4) {
        const int b = idx / (Nn * 8);
        const int r = idx - b * (Nn * 8);
        const int n = r >> 3;
        const int c4 = r & 7;
        out4[idx] = obs4[((long)b * Tt + n + WL - 1) * 8 + c4];
      } else {
        const int j = idx - total4;
        const int b = j / Nn;
        const int n = j - b * Nn;
        out[OFF_LAB + j] = (float)tlab[(long)b * Tt + n + WL - 1];
      }
    }
    return;
  }

  const int lane = tid & 15;
  const int sub = tid >> 4;
  const int blk = blockIdx.x;
  const int g = (blk << 2) + sub;

  const float sc[6] = {-LOG2E, -LOG2E, -LOG2E, -LOG2E, 2.f * LOG2E, 2.f * LOG2E};
  float wih8[6], wih9[6], whh0[6], whh1[6], bhhv[6];
#pragma unroll
  for (int q = 0; q < 6; ++q) {
    wih8[q] = Wih[8 * 6 + q] * sc[q];
    wih9[q] = Wih[9 * 6 + q] * sc[q];
    whh0[q] = Whh[q] * sc[q];
    whh1[q] = Whh[6 + q] * sc[q];
    bhhv[q] = bhh[q] * sc[q];
  }
  const float w1c0 = pW1[lane], w1c1 = pW1[16 + lane], b1v = pb1[lane];
  constexpr int otab[16] = {0, 1, 2, 3, 7, 6, 5, 4, 8, 9, 10, 11, 15, 14, 13, 12};
  float wg[16];
#pragma unroll
  for (int i = 0; i < 16; ++i) wg[i] = pW2[(lane ^ otab[i]) * 16 + lane];
  const float b2v = pb2[lane];
  const float w3a = pW3[lane * 2], w3b = pW3[lane * 2 + 1];
  const float b3a = pb3[0], b3b = pb3[1];

  const float* priors = out + OFF_PRIORS;
  const long pbase = (long)g * Nn;
  const float* gsrc = rec + (long)blk * (REC_T * 32);
  float* xw = out + OFF_XTRAJ + pbase * 2 + 2;
  float* sw = out + OFF_POSTS + pbase * 2 + 2;

  const float2 s0v = *reinterpret_cast<const float2*>(priors + pbase * 2);
  float x0p = 0.f, x1p = 0.f;
  float s0p = s0v.x, s1p = s0v.y;
  if (lane == 0)
    *reinterpret_cast<float2*>(out + OFF_XTRAJ + pbase * 2) =
        make_float2(0.f, 0.f);
  if (lane == 1)
    *reinterpret_cast<float2*>(out + OFF_POSTS + pbase * 2) =
        make_float2(s0p, s1p);

  float4 st0, st1;
  LOADCH(0);
  WRITECH(0);
  LOADCH(1);   // chunk 1 in flight during chunk 0's compute

  // prefetch step (0,0)
  float4 cGA, cGB;
  {
    const float* rp = &slds[0][(sub)*8];
    cGA = *reinterpret_cast<const float4*>(rp);
    cGB = *reinterpret_cast<const float4*>(rp + 4);
  }

  int tg = 0;
  for (int c = 0; c < 32; ++c) {
    const int buf = c & 1;
    if (c + 1 < 32) WRITECH((c + 1) & 1);
    if (c + 2 < 32) LOADCH(c + 2);
#pragma unroll
    for (int tl = 0; tl < 16; ++tl) {
      const float4 GA = cGA;
      const float4 GB = cGB;
      const int ntl = (tl + 1) & 15;
      const int nbuf = (tl == 15) ? (buf ^ 1) : buf;
      const float* rp = &slds[nbuf][(ntl * 4 + sub) * 8];
      cGA = *reinterpret_cast<const float4*>(rp);
      cGB = *reinterpret_cast<const float4*>(rp + 4);
      SCAN_STEP(GA, GB, tg);
      ++tg;
    }
  }
}

// ---------------- fallback scan (no workspace) ----------------
__global__ __launch_bounds__(64) void scan_fb_kernel(
    const float* __restrict__ act, const int* __restrict__ mask,
    const float* __restrict__ Wih, const float* __restrict__ Whh,
    const float* __restrict__ bih, const float* __restrict__ bhh,
    const float* __restrict__ pW1, const float* __restrict__ pb1,
    const float* __restrict__ pW2, const float* __restrict__ pb2,
    const float* __restrict__ pW3, const float* __restrict__ pb3,
    float* __restrict__ out) {
  const int tid = threadIdx.x;
  const int lane = tid & 15;
  const int g = (blockIdx.x * 64 + tid) >> 4;

  float wih8[6], wih9[6], whh0[6], whh1[6], bhhv[6], bihv[6];
  float wihA[8][6];
#pragma unroll
  for (int q = 0; q < 6; ++q) {
    wih8[q] = Wih[8 * 6 + q];
    wih9[q] = Wih[9 * 6 + q];
    whh0[q] = Whh[q];
    whh1[q] = Whh[6 + q];
    bhhv[q] = bhh[q];
    bihv[q] = bih[q];
  }
#pragma unroll
  for (int i = 0; i < 8; ++i)
#pragma unroll
    for (int q = 0; q < 6; ++q) wihA[i][q] = Wih[i * 6 + q];

  const float w1c0 = pW1[lane], w1c1 = pW1[16 + lane], b1v = pb1[lane];
  float w2c[16];
#pragma unroll
  for (int k = 0; k < 16; ++k) w2c[k] = pW2[k * 16 + lane];
  const float b2v = pb2[lane];
  const float w3a = pW3[lane * 2], w3b = pW3[lane * 2 + 1];
  const float b3a = pb3[0], b3b = pb3[1];

  const float* priors = out + OFF_PRIORS;
  float* posts = out + OFF_POSTS;
  float* xtraj = out + OFF_XTRAJ;
  const long pbase = (long)g * Nn;
  const float* aptr = act + ((long)g * Tt + WL - 1) * 8;

  const float2 s0v = *reinterpret_cast<const float2*>(priors + pbase * 2);
  float x0p = 0.f, x1p = 0.f;
  float s0p = s0v.x, s1p = s0v.y;
  if (lane == 0)
    *reinterpret_cast<float2*>(xtraj + pbase * 2) = make_float2(0.f, 0.f);
  if (lane == 1)
    *reinterpret_cast<float2*>(posts + pbase * 2) = make_float2(s0p, s1p);

  float4 an0 = *reinterpret_cast<const float4*>(aptr);
  float4 an1 = *reinterpret_cast<const float4*>(aptr + 4);
  float2 prn = s0v;
  int mn = mask[pbase];

  for (int t = 0; t < Nn - 1; ++t) {
    const float4 a0 = an0, a1 = an1;
    const float2 pr = prn;
    const int m = mn;
    const int tn1 = (t + 1 < Nn - 1) ? t + 1 : Nn - 2;
    an0 = *reinterpret_cast<const float4*>(aptr + (long)tn1 * 8);
    an1 = *reinterpret_cast<const float4*>(aptr + (long)tn1 * 8 + 4);
    prn = *reinterpret_cast<const float2*>(priors + (pbase + t + 1) * 2);
    mn = mask[pbase + t + 1];

    const float st0 = m ? pr.x : s0p;
    const float st1 = m ? pr.y : s1p;

    float giq[6], ghq[6];
#pragma unroll
    for (int q = 0; q < 6; ++q) {
      float acc = bihv[q];
      acc = fmaf(a0.x, wihA[0][q], acc);
      acc = fmaf(a0.y, wihA[1][q], acc);
      acc = fmaf(a0.z, wihA[2][q], acc);
      acc = fmaf(a0.w, wihA[3][q], acc);
      acc = fmaf(a1.x, wihA[4][q], acc);
      acc = fmaf(a1.y, wihA[5][q], acc);
      acc = fmaf(a1.z, wihA[6][q], acc);
      acc = fmaf(a1.w, wihA[7][q], acc);
      giq[q] = fmaf(st1, wih9[q], fmaf(st0, wih8[q], acc));
      ghq[q] = fmaf(x1p, whh1[q], fmaf(x0p, whh0[q], bhhv[q]));
    }
    const float r0 = sigmoidf_(giq[0] + ghq[0]);
    const float r1 = sigmoidf_(giq[1] + ghq[1]);
    const float z0 = sigmoidf_(giq[2] + ghq[2]);
    const float z1 = sigmoidf_(giq[3] + ghq[3]);
    const float nn0 = tanh_(fmaf(r0, ghq[4], giq[4]));
    const float nn1 = tanh_(fmaf(r1, ghq[5], giq[5]));
    const float xn0 = fmaf(z0, x0p - nn0, nn0);
    const float xn1 = fmaf(z1, x1p - nn1, nn1);

    const float h1 = fmaxf(fmaf(xn1, w1c1, fmaf(xn0, w1c0, b1v)), 0.0f);
    float ha[16];
#pragma unroll
    for (int k = 0; k < 16; ++k) ha[k] = __shfl(h1, k, 16);
    float q0 = fmaf(ha[0], w2c[0], b2v);
    q0 = fmaf(ha[1], w2c[1], q0);
    q0 = fmaf(ha[2], w2c[2], q0);
    q0 = fmaf(ha[3], w2c[3], q0);
    float q1 = ha[4] * w2c[4];
    q1 = fmaf(ha[5], w2c[5], q1);
    q1 = fmaf(ha[6], w2c[6], q1);
    q1 = fmaf(ha[7], w2c[7], q1);
    float q2 = ha[8] * w2c[8];
    q2 = fmaf(ha[9], w2c[9], q2);
    q2 = fmaf(ha[10], w2c[10], q2);
    q2 = fmaf(ha[11], w2c[11], q2);
    float q3 = ha[12] * w2c[12];
    q3 = fmaf(ha[13], w2c[13], q3);
    q3 = fmaf(ha[14], w2c[14], q3);
    q3 = fmaf(ha[15], w2c[15], q3);
    const float h2 = fmaxf((q0 + q1) + (q2 + q3), 0.0f);

    float p0 = row16_allsum(h2 * w3a);
    float p1 = row16_allsum(h2 * w3b);
    const float sn0 = p0 + b3a;
    const float sn1 = p1 + b3b;

    if (lane == 0)
      *reinterpret_cast<float2*>(xtraj + (pbase + t + 1) * 2) =
          make_float2(xn0, xn1);
    if (lane == 1)
      *reinterpret_cast<float2*>(posts + (pbase + t + 1) * 2) =
          make_float2(sn0, sn1);
    x0p = xn0; x1p = xn1; s0p = sn0; s1p = sn1;
  }
}

}  // namespace

extern "C" void kernel_launch(void* const* d_in, const int* in_sizes, int n_in,
                              void* d_out, int out_size, void* d_ws, size_t ws_size,
                              hipStream_t stream) {
  const float* obs    = (const float*)d_in[0];
  const float* action = (const float*)d_in[1];
  const int* t_label  = (const int*)d_in[2];
  const int* mask     = (const int*)d_in[3];
  const float* enc_W1 = (const float*)d_in[4];
  const float* enc_b1 = (const float*)d_in[5];
  const float* enc_W2 = (const float*)d_in[6];
  const float* enc_b2 = (const float*)d_in[7];
  const float* enc_W3 = (const float*)d_in[8];
  const float* enc_b3 = (const float*)d_in[9];
  const float* gru_Wih = (const float*)d_in[10];
  const float* gru_Whh = (const float*)d_in[11];
  const float* gru_bih = (const float*)d_in[12];
  const float* gru_bhh = (const float*)d_in[13];
  const float* post_W1 = (const float*)d_in[14];
  const float* post_b1 = (const float*)d_in[15];
  const float* post_W2 = (const float*)d_in[16];
  const float* post_b2 = (const float*)d_in[17];
  const float* post_W3 = (const float*)d_in[18];
  const float* post_b3 = (const float*)d_in[19];
  const float* dec_W1 = (const float*)d_in[20];
  const float* dec_b1 = (const float*)d_in[21];
  const float* dec_W2 = (const float*)d_in[22];
  const float* dec_b2 = (const float*)d_in[23];
  const float* dec_W3 = (const float*)d_in[24];
  const float* dec_b3 = (const float*)d_in[25];
  float* out = (float*)d_out;

  pack_kernel<<<(PK_TOTAL + 255) / 256, 256, 0, stream>>>(
      enc_W1, enc_W2, enc_W3, dec_W1, dec_W2, dec_W3);

  const size_t rec_bytes = (size_t)Bb * REC_T * 8 * sizeof(float);
  const bool use_ws = (ws_size >= rec_bytes);
  float* rec = use_ws ? (float*)d_ws : nullptr;

  enc_mfma<<<Bb * 8, 256, 0, stream>>>(obs, action, enc_b1, enc_b2, enc_b3,
                                       mask, gru_Wih, gru_bih, rec, out);

  if (use_ws) {
    // scan blocks [0,128) + fused copy blocks [128, 2176)
    scan4_kernel<<<128 + 2048, 64, 0, stream>>>(
        rec, post_W2, post_W1, post_b1, post_b2, post_W3, post_b3, gru_Wih,
        gru_Whh, gru_bhh, obs, t_label, out);
  } else {
    scan_fb_kernel<<<128, 64, 0, stream>>>(
        action, mask, gru_Wih, gru_Whh, gru_bih, gru_bhh, post_W1, post_b1,
        post_W2, post_b2, post_W3, post_b3, out);
    copy_kernel<<<2048, 256, 0, stream>>>(obs, t_label, out);
  }

  dec_mfma<<<Bb * 8, 256, 0, stream>>>(action, dec_b1, dec_b2, dec_b3, out);
}